// Round 7
// baseline (309.323 us; speedup 1.0000x reference)
//
#include <hip/hip_runtime.h>
#include <math.h>

#define NS 20000
#define TT 6890
#define TPAD 6912
#define FE 128
#define EDG 640000
#define DEG 32

#define NCH 4             // T-chunks per block (one per wave)
#define CHCOLS 1728       // 6912/4
#define SPC 54            // 32-col strips per chunk
#define ROWS_PB 32        // rows per block (each wave covers all 32)

typedef __attribute__((ext_vector_type(8))) short short8;     // 8 bf16
typedef __attribute__((ext_vector_type(4))) float floatx4;    // MFMA C/D
typedef unsigned int uint;

__device__ __forceinline__ unsigned short f2bf(float f) {
  unsigned int u = __float_as_uint(f);
  return (unsigned short)((u + 0x7fffu + ((u >> 16) & 1u)) >> 16);  // RNE
}

// ---------------- K0: target norms (+biased copy) + bf16 cast, padded ----------------
__global__ void tn_cast_kernel(const float* __restrict__ tf, float* __restrict__ tn,
                               float* __restrict__ tn256,
                               unsigned short* __restrict__ tfb) {
  int gid = blockIdx.x * blockDim.x + threadIdx.x;
  int w = gid >> 6;
  int lane = gid & 63;
  if (w >= TPAD) return;
  if (w < TT) {
    const float* p = tf + (size_t)w * FE;
    float a = p[lane];
    float b = p[lane + 64];
    float s = a * a + b * b;
#pragma unroll
    for (int off = 32; off > 0; off >>= 1) s += __shfl_xor(s, off);
    if (lane == 0) { tn[w] = s; tn256[w] = s + 256.0f; }
    float c0 = p[2 * lane], c1 = p[2 * lane + 1];
    ushort2 o;
    o.x = f2bf(c0);
    o.y = f2bf(c1);
    *reinterpret_cast<ushort2*>(tfb + (size_t)w * FE + 2 * lane) = o;
  } else {
    if (lane == 0) { tn[w] = 1e30f; tn256[w] = 3e38f; }  // pads never selected
    ushort2 z; z.x = 0; z.y = 0;
    *reinterpret_cast<ushort2*>(tfb + (size_t)w * FE + 2 * lane) = z;
  }
}

// ---------------- K1: wave-private LDS stream, barrier-free K-loop ----------------
// Block = 32 rows, 4 waves; wave w owns T-chunk w (54 strips x 32 cols) with a
// private double-buffered XOR-swizzled LDS tile (16B chunk c of col stored at
// c ^ (col&7): ds_read/ds_write both hit the 8-cyc/KB optimum). MFMA:
// A = target strip (D-row = tcol), B = 2x16 source rows. Per-(lane,h) top-6
// packed keys: key = (bits(tn+256-2dp) & ~0x1FFF) | col (uint order == float
// order, metric > 0). No __syncthreads in the main loop (wave-local LDS only).
union SmemU {
  unsigned short tile[NCH][2][4096];   // 4 waves x 2 bufs x 8 KB = 64 KB
  struct {
    uint  pk[ROWS_PB][25];             // 24 merged candidates + pad
    float pv[ROWS_PB][25];
  } e;
};

__global__ __launch_bounds__(256, 2) void topk_kernel(
    const float* __restrict__ sf, const float* __restrict__ tf,
    const unsigned short* __restrict__ tfb, const float* __restrict__ tn,
    const float* __restrict__ tn256, const float* __restrict__ tp,
    float* __restrict__ pred) {
  __shared__ SmemU u;
  const int tid = threadIdx.x;
  const int lane = tid & 63;
  const int wv = tid >> 6;             // chunk id 0..3
  const int q = lane >> 4;
  const int m = lane & 15;
  const int row0 = blockIdx.x * ROWS_PB;   // exact: 625*32 = 20000

  // resident B-operand fragments: rows row0 + h*16 + m
  short8 bf00, bf01, bf02, bf03, bf10, bf11, bf12, bf13;
#pragma unroll
  for (int h = 0; h < 2; ++h) {
    const float* src = sf + (size_t)(row0 + h * 16 + m) * FE;
#pragma unroll
    for (int ks = 0; ks < 4; ++ks) {
      float4 f0 = *reinterpret_cast<const float4*>(src + ks * 32 + q * 8);
      float4 f1 = *reinterpret_cast<const float4*>(src + ks * 32 + q * 8 + 4);
      union { unsigned short us[8]; short8 s8; } t;
      t.us[0] = f2bf(f0.x); t.us[1] = f2bf(f0.y);
      t.us[2] = f2bf(f0.z); t.us[3] = f2bf(f0.w);
      t.us[4] = f2bf(f1.x); t.us[5] = f2bf(f1.y);
      t.us[6] = f2bf(f1.z); t.us[7] = f2bf(f1.w);
      if (h == 0) { if (ks == 0) bf00 = t.s8; else if (ks == 1) bf01 = t.s8;
                    else if (ks == 2) bf02 = t.s8; else bf03 = t.s8; }
      else        { if (ks == 0) bf10 = t.s8; else if (ks == 1) bf11 = t.s8;
                    else if (ks == 2) bf12 = t.s8; else bf13 = t.s8; }
    }
  }

  uint kq[2][6];
#pragma unroll
  for (int h = 0; h < 2; ++h)
#pragma unroll
    for (int k = 0; k < 6; ++k) kq[h][k] = 0xFFFFFFFFu;

  // swizzled read offsets (shorts), invariant over strips: ((4ks+q)^(m&7))*8
  int sw0 = ((0 * 4 + q) ^ (m & 7)) << 3;
  int sw1 = ((1 * 4 + q) ^ (m & 7)) << 3;
  int sw2 = ((2 * 4 + q) ^ (m & 7)) << 3;
  int sw3 = ((3 * 4 + q) ^ (m & 7)) << 3;

  const int chunk0 = wv * CHCOLS;
  const int s0 = blockIdx.x % SPC;     // stagger strip order across blocks
  const int scol = lane >> 1;          // staging col 0..31
  const int shalf = lane & 1;
  // staging LDS dst offsets (shorts): scol*128 + ((8*shalf+j)^(scol&7))*8
  int wd[8];
#pragma unroll
  for (int j = 0; j < 8; ++j) wd[j] = scol * 128 + (((shalf << 3) | j) ^ (scol & 7)) * 8;
  const int gsb = scol * 128 + shalf * 64;   // staging global base (shorts, per strip)

  uint4 st0, st1, st2, st3, st4, st5, st6, st7;

  // prologue: stage strip s0 into buf 0
  {
    const unsigned short* g = tfb + (size_t)(chunk0 + s0 * 32) * FE + gsb;
    st0 = *reinterpret_cast<const uint4*>(g);
    st1 = *reinterpret_cast<const uint4*>(g + 8);
    st2 = *reinterpret_cast<const uint4*>(g + 16);
    st3 = *reinterpret_cast<const uint4*>(g + 24);
    st4 = *reinterpret_cast<const uint4*>(g + 32);
    st5 = *reinterpret_cast<const uint4*>(g + 40);
    st6 = *reinterpret_cast<const uint4*>(g + 48);
    st7 = *reinterpret_cast<const uint4*>(g + 56);
    unsigned short* d = &u.tile[wv][0][0];
    *reinterpret_cast<uint4*>(d + wd[0]) = st0;
    *reinterpret_cast<uint4*>(d + wd[1]) = st1;
    *reinterpret_cast<uint4*>(d + wd[2]) = st2;
    *reinterpret_cast<uint4*>(d + wd[3]) = st3;
    *reinterpret_cast<uint4*>(d + wd[4]) = st4;
    *reinterpret_cast<uint4*>(d + wd[5]) = st5;
    *reinterpret_cast<uint4*>(d + wd[6]) = st6;
    *reinterpret_cast<uint4*>(d + wd[7]) = st7;
  }

  for (int ss = 0; ss < SPC; ++ss) {
    const int p = ss & 1;
    int s = s0 + ss; if (s >= SPC) s -= SPC;
    const int col0 = chunk0 + s * 32;

    // prefetch next strip into registers (stays in flight during compute)
    if (ss + 1 < SPC) {
      int s1 = s0 + ss + 1; if (s1 >= SPC) s1 -= SPC;
      const unsigned short* g = tfb + (size_t)(chunk0 + s1 * 32) * FE + gsb;
      st0 = *reinterpret_cast<const uint4*>(g);
      st1 = *reinterpret_cast<const uint4*>(g + 8);
      st2 = *reinterpret_cast<const uint4*>(g + 16);
      st3 = *reinterpret_cast<const uint4*>(g + 24);
      st4 = *reinterpret_cast<const uint4*>(g + 32);
      st5 = *reinterpret_cast<const uint4*>(g + 40);
      st6 = *reinterpret_cast<const uint4*>(g + 48);
      st7 = *reinterpret_cast<const uint4*>(g + 56);
    }

    float4 tn0 = *reinterpret_cast<const float4*>(tn256 + col0 + q * 4);
    float4 tn1 = *reinterpret_cast<const float4*>(tn256 + col0 + 16 + q * 4);

    const unsigned short* tb = &u.tile[wv][p][0];
#pragma unroll
    for (int a = 0; a < 2; ++a) {
      const unsigned short* ab = tb + a * 2048 + m * 128;
      short8 a0 = *reinterpret_cast<const short8*>(ab + sw0);
      short8 a1 = *reinterpret_cast<const short8*>(ab + sw1);
      short8 a2 = *reinterpret_cast<const short8*>(ab + sw2);
      short8 a3 = *reinterpret_cast<const short8*>(ab + sw3);
      floatx4 acc0 = (floatx4){0.f, 0.f, 0.f, 0.f};
      floatx4 acc1 = (floatx4){0.f, 0.f, 0.f, 0.f};
      acc0 = __builtin_amdgcn_mfma_f32_16x16x32_bf16(a0, bf00, acc0, 0, 0, 0);
      acc1 = __builtin_amdgcn_mfma_f32_16x16x32_bf16(a0, bf10, acc1, 0, 0, 0);
      acc0 = __builtin_amdgcn_mfma_f32_16x16x32_bf16(a1, bf01, acc0, 0, 0, 0);
      acc1 = __builtin_amdgcn_mfma_f32_16x16x32_bf16(a1, bf11, acc1, 0, 0, 0);
      acc0 = __builtin_amdgcn_mfma_f32_16x16x32_bf16(a2, bf02, acc0, 0, 0, 0);
      acc1 = __builtin_amdgcn_mfma_f32_16x16x32_bf16(a2, bf12, acc1, 0, 0, 0);
      acc0 = __builtin_amdgcn_mfma_f32_16x16x32_bf16(a3, bf03, acc0, 0, 0, 0);
      acc1 = __builtin_amdgcn_mfma_f32_16x16x32_bf16(a3, bf13, acc1, 0, 0, 0);

      float tv[4];
      if (a == 0) { tv[0] = tn0.x; tv[1] = tn0.y; tv[2] = tn0.z; tv[3] = tn0.w; }
      else        { tv[0] = tn1.x; tv[1] = tn1.y; tv[2] = tn1.z; tv[3] = tn1.w; }
      const uint cb = (uint)(col0 + a * 16 + q * 4);
#pragma unroll
      for (int r = 0; r < 4; ++r) {
        float met0 = fmaf(-2.f, acc0[r], tv[r]);         // > 0 always
        float met1 = fmaf(-2.f, acc1[r], tv[r]);
        uint t0 = (__float_as_uint(met0) & 0xFFFFE000u) | (cb + (uint)r);
        uint t1 = (__float_as_uint(met1) & 0xFFFFE000u) | (cb + (uint)r);
#pragma unroll
        for (int k = 0; k < 6; ++k) {                     // branchless inserts
          uint lo0 = min(kq[0][k], t0), hi0 = max(kq[0][k], t0);
          kq[0][k] = lo0; t0 = hi0;
          uint lo1 = min(kq[1][k], t1), hi1 = max(kq[1][k], t1);
          kq[1][k] = lo1; t1 = hi1;
        }
      }
    }

    // write prefetched strip into the other private buffer (no barrier needed)
    if (ss + 1 < SPC) {
      unsigned short* d = &u.tile[wv][p ^ 1][0];
      *reinterpret_cast<uint4*>(d + wd[0]) = st0;
      *reinterpret_cast<uint4*>(d + wd[1]) = st1;
      *reinterpret_cast<uint4*>(d + wd[2]) = st2;
      *reinterpret_cast<uint4*>(d + wd[3]) = st3;
      *reinterpret_cast<uint4*>(d + wd[4]) = st4;
      *reinterpret_cast<uint4*>(d + wd[5]) = st5;
      *reinterpret_cast<uint4*>(d + wd[6]) = st6;
      *reinterpret_cast<uint4*>(d + wd[7]) = st7;
    }
  }

  // butterfly shfl merge across the 4 q-lanes -> top-6 of this wave's chunk
#pragma unroll
  for (int h = 0; h < 2; ++h) {
#pragma unroll
    for (int st = 16; st <= 32; st <<= 1) {
      uint inc[6];
#pragma unroll
      for (int k = 0; k < 6; ++k) inc[k] = __shfl_xor(kq[h][k], st);
#pragma unroll
      for (int k = 0; k < 6; ++k) {
        uint t = inc[k];
#pragma unroll
        for (int j = 0; j < 6; ++j) {
          uint lo = min(kq[h][j], t);
          uint hi = max(kq[h][j], t);
          kq[h][j] = lo;
          t = hi;
        }
      }
    }
  }
  __syncthreads();   // all waves done with tiles; safe to overlay epilogue
  if (q == 0) {
#pragma unroll
    for (int h = 0; h < 2; ++h)
#pragma unroll
      for (int k = 0; k < 6; ++k) u.e.pk[h * 16 + m][wv * 6 + k] = kq[h][k];
  }
  __syncthreads();

  // fp32 rescore (exact round-1 arithmetic): 32 rows x 24 cands = 768 dots
#pragma unroll
  for (int j = 0; j < 3; ++j) {
    int idx = j * 256 + tid;            // < 768
    int r = idx / 24;
    int c = idx - r * 24;
    int col = (int)(u.e.pk[r][c] & 0x1FFFu);
    const float* srow = sf + (size_t)(row0 + r) * FE;
    const float* trow = tf + (size_t)col * FE;
    float accv = 0.f;
#pragma unroll 8
    for (int kk = 0; kk < FE; kk += 4) {
      float4 av = *reinterpret_cast<const float4*>(srow + kk);
      float4 bv = *reinterpret_cast<const float4*>(trow + kk);
      accv += av.x * bv.x + av.y * bv.y + av.z * bv.z + av.w * bv.w;
    }
    u.e.pv[r][c] = tn[col] - 2.f * accv;
  }
  __syncthreads();

  // exact top-6 of 24, softmax, gather
  if (tid < ROWS_PB) {
    float sd[6]; int sp6[6];
#pragma unroll
    for (int k = 0; k < 6; ++k) { sd[k] = 1e30f; sp6[k] = 0; }
    for (int j = 0; j < 24; ++j) {
      float v = u.e.pv[tid][j];
      if (v < sd[5]) {
        sd[5] = v; sp6[5] = j;
#pragma unroll
        for (int k = 4; k >= 0; --k) {
          if (sd[k + 1] < sd[k]) {
            float tvv = sd[k]; sd[k] = sd[k + 1]; sd[k + 1] = tvv;
            int tii = sp6[k]; sp6[k] = sp6[k + 1]; sp6[k + 1] = tii;
          }
        }
      }
    }
    float wgt[6]; float wsum = 0.f;
#pragma unroll
    for (int k = 0; k < 6; ++k) { wgt[k] = __expf(sd[0] - sd[k]); wsum += wgt[k]; }
    float inv = 1.f / wsum;
    float px = 0.f, py = 0.f, pz = 0.f;
#pragma unroll
    for (int k = 0; k < 6; ++k) {
      float sc = wgt[k] * inv;
      const float* qq = tp + (size_t)(u.e.pk[tid][sp6[k]] & 0x1FFFu) * 3;
      px += sc * qq[0]; py += sc * qq[1]; pz += sc * qq[2];
    }
    int g = row0 + tid;
    pred[g * 3 + 0] = px;
    pred[g * 3 + 1] = py;
    pred[g * 3 + 2] = pz;
  }
}

// ---------------- K2: per-node Procrustes (3x3 SVD, fp64 Jacobi) ----------------
__global__ __launch_bounds__(256) void proc_kernel(
    const int* __restrict__ colp, const float* __restrict__ pos,
    const float* __restrict__ pred, float* __restrict__ Rout,
    float* __restrict__ tout, float* __restrict__ qnorm) {
  int i = blockIdx.x * blockDim.x + threadIdx.x;
  if (i >= NS) return;
  double sp[3] = {0, 0, 0}, sq[3] = {0, 0, 0};
  double spq[3][3] = {{0, 0, 0}, {0, 0, 0}, {0, 0, 0}};
  const int* ci = colp + i * DEG;
  for (int e = 0; e < DEG; ++e) {
    int c = ci[e];
    double p0 = pos[c * 3], p1 = pos[c * 3 + 1], p2 = pos[c * 3 + 2];
    double q0 = pred[c * 3], q1 = pred[c * 3 + 1], q2 = pred[c * 3 + 2];
    sp[0] += p0; sp[1] += p1; sp[2] += p2;
    sq[0] += q0; sq[1] += q1; sq[2] += q2;
    spq[0][0] += p0 * q0; spq[0][1] += p0 * q1; spq[0][2] += p0 * q2;
    spq[1][0] += p1 * q0; spq[1][1] += p1 * q1; spq[1][2] += p1 * q2;
    spq[2][0] += p2 * q0; spq[2][1] += p2 * q1; spq[2][2] += p2 * q2;
  }
  const double inv = 1.0 / 32.0;
  double A[3][3], sc[3], tcn[3];
  for (int a = 0; a < 3; ++a) {
    sc[a] = sp[a] * inv;
    tcn[a] = sq[a] * inv;
  }
  for (int a = 0; a < 3; ++a)
    for (int b = 0; b < 3; ++b) A[a][b] = spq[a][b] - sp[a] * sq[b] * inv;

  double S[3][3];
  for (int a = 0; a < 3; ++a)
    for (int b = 0; b < 3; ++b)
      S[a][b] = A[0][a] * A[0][b] + A[1][a] * A[1][b] + A[2][a] * A[2][b];
  double V[3][3] = {{1, 0, 0}, {0, 1, 0}, {0, 0, 1}};
  const int JP[3] = {0, 0, 1}, JQ[3] = {1, 2, 2};
  for (int sweep = 0; sweep < 6; ++sweep) {
    for (int r = 0; r < 3; ++r) {
      int p = JP[r], q = JQ[r];
      double apq = S[p][q];
      if (fabs(apq) < 1e-300) continue;
      double theta = (S[q][q] - S[p][p]) / (2.0 * apq);
      double t = copysign(1.0 / (fabs(theta) + sqrt(theta * theta + 1.0)), theta);
      double c = 1.0 / sqrt(t * t + 1.0);
      double s = t * c;
      double spp = S[p][p], sqq = S[q][q];
      S[p][p] = spp - t * apq;
      S[q][q] = sqq + t * apq;
      S[p][q] = 0.0; S[q][p] = 0.0;
      int k = 3 - p - q;
      double skp = S[k][p], skq = S[k][q];
      S[k][p] = S[p][k] = c * skp - s * skq;
      S[k][q] = S[q][k] = s * skp + c * skq;
      for (int mth = 0; mth < 3; ++mth) {
        double vp = V[mth][p], vq = V[mth][q];
        V[mth][p] = c * vp - s * vq;
        V[mth][q] = s * vp + c * vq;
      }
    }
  }
  double lam[3] = {S[0][0], S[1][1], S[2][2]};
  int i0 = 0, i1 = 1, i2 = 2, tmp;
  if (lam[i0] < lam[i1]) { tmp = i0; i0 = i1; i1 = tmp; }
  if (lam[i0] < lam[i2]) { tmp = i0; i0 = i2; i2 = tmp; }
  if (lam[i1] < lam[i2]) { tmp = i1; i1 = i2; i2 = tmp; }
  double v0[3] = {V[0][i0], V[1][i0], V[2][i0]};
  double v1[3] = {V[0][i1], V[1][i1], V[2][i1]};
  double v2[3] = {V[0][i2], V[1][i2], V[2][i2]};

  double Av0[3], Av1[3], Av2[3];
  for (int a = 0; a < 3; ++a) {
    Av0[a] = A[a][0] * v0[0] + A[a][1] * v0[1] + A[a][2] * v0[2];
    Av1[a] = A[a][0] * v1[0] + A[a][1] * v1[1] + A[a][2] * v1[2];
    Av2[a] = A[a][0] * v2[0] + A[a][1] * v2[1] + A[a][2] * v2[2];
  }
  double n0 = fmax(sqrt(Av0[0]*Av0[0] + Av0[1]*Av0[1] + Av0[2]*Av0[2]), 1e-300);
  double u0[3] = {Av0[0] / n0, Av0[1] / n0, Av0[2] / n0};
  double proj = u0[0]*Av1[0] + u0[1]*Av1[1] + u0[2]*Av1[2];
  double u1[3] = {Av1[0] - proj * u0[0], Av1[1] - proj * u0[1], Av1[2] - proj * u0[2]};
  double n1 = fmax(sqrt(u1[0]*u1[0] + u1[1]*u1[1] + u1[2]*u1[2]), 1e-300);
  u1[0] /= n1; u1[1] /= n1; u1[2] /= n1;
  double w[3] = {u0[1]*u1[2] - u0[2]*u1[1],
                 u0[2]*u1[0] - u0[0]*u1[2],
                 u0[0]*u1[1] - u0[1]*u1[0]};
  double dotw = Av2[0]*w[0] + Av2[1]*w[1] + Av2[2]*w[2];
  double sgn = (dotw < 0.0) ? -1.0 : 1.0;
  double detA = A[0][0]*(A[1][1]*A[2][2] - A[1][2]*A[2][1])
              - A[0][1]*(A[1][0]*A[2][2] - A[1][2]*A[2][0])
              + A[0][2]*(A[1][0]*A[2][1] - A[1][1]*A[2][0]);
  double d3 = ((detA < 0.0) ? -1.0 : 1.0) * sgn;

  double R[3][3];
  for (int a = 0; a < 3; ++a)
    for (int b = 0; b < 3; ++b)
      R[a][b] = u0[a]*v0[b] + u1[a]*v1[b] + d3 * w[a]*v2[b];

  for (int a = 0; a < 3; ++a)
    for (int b = 0; b < 3; ++b) Rout[i * 9 + a * 3 + b] = (float)R[a][b];
  double tr_[3];
  for (int a = 0; a < 3; ++a) {
    tr_[a] = tcn[a] - (R[a][0]*sc[0] + R[a][1]*sc[1] + R[a][2]*sc[2]);
    tout[i * 3 + a] = (float)tr_[a];
  }
  double pxi = pos[i * 3], pyi = pos[i * 3 + 1], pzi = pos[i * 3 + 2];
  double r0 = R[0][0]*pxi + R[0][1]*pyi + R[0][2]*pzi + tr_[0] - pred[i * 3];
  double r1 = R[1][0]*pxi + R[1][1]*pyi + R[1][2]*pzi + tr_[1] - pred[i * 3 + 1];
  double r2 = R[2][0]*pxi + R[2][1]*pyi + R[2][2]*pzi + tr_[2] - pred[i * 3 + 2];
  qnorm[i] = (float)(r0 * r0 + r1 * r1 + r2 * r2);
}

// ---------------- K3: per-node residual mean over neighbors ----------------
__global__ __launch_bounds__(256) void dst_kernel(
    const int* __restrict__ colp, const float* __restrict__ qn,
    float* __restrict__ dout) {
  int i = blockIdx.x * blockDim.x + threadIdx.x;
  if (i >= NS) return;
  const int* ci = colp + i * DEG;
  float s = 0.f;
#pragma unroll
  for (int e = 0; e < DEG; ++e) s += qn[ci[e]];
  dout[i] = s * (1.0f / 32.0f);
}

extern "C" void kernel_launch(void* const* d_in, const int* in_sizes, int n_in,
                              void* d_out, int out_size, void* d_ws, size_t ws_size,
                              hipStream_t stream) {
  const float* sf  = (const float*)d_in[0];   // [N,128]
  const float* tf  = (const float*)d_in[1];   // [T,128]
  const float* tp  = (const float*)d_in[2];   // [T,3]
  const float* pos = (const float*)d_in[3];   // [N,3]
  const int*   ei  = (const int*)d_in[4];     // [2,E]
  float* out = (float*)d_out;                 // [N*9 | N*3 | N]
  char* ws = (char*)d_ws;
  // ws layout (~2.07 MB; qn aliases tfb which is dead after topk):
  float*          tn    = (float*)(ws);                   // 27,648 B
  float*          tn256 = (float*)(ws + 28672);           // 27,648 B
  float*          pred  = (float*)(ws + 57344);           // 240,000 B
  unsigned short* tfb   = (unsigned short*)(ws + 297472); // 1,769,472 B
  float*          qn    = (float*)(ws + 297472);          // alias (post-topk)
  const int* colp = ei + EDG;

  tn_cast_kernel<<<(TPAD * 64) / 256, 256, 0, stream>>>(tf, tn, tn256, tfb);
  topk_kernel<<<NS / ROWS_PB, 256, 0, stream>>>(sf, tf, tfb, tn, tn256, tp, pred);
  proc_kernel<<<(NS + 255) / 256, 256, 0, stream>>>(colp, pos, pred, out,
                                                    out + NS * 9, qn);
  dst_kernel<<<(NS + 255) / 256, 256, 0, stream>>>(colp, qn, out + NS * 12);
}